// Round 4
// baseline (246.514 us; speedup 1.0000x reference)
//
#include <hip/hip_runtime.h>
#include <hip/hip_bf16.h>

// ---- problem constants ----
#define NN 25000
#define PP 100000
#define TT 4
#define DD 128
#define LEAKY 0.001f

#define PB 16          // propers per block
#define ROWS 64        // PB * TT rows of the MLP per block

typedef __bf16 bf16;
typedef __bf16 bf16x8 __attribute__((ext_vector_type(8)));
typedef float  f32x4  __attribute__((ext_vector_type(4)));

// ---- workspace layout (bytes) ----
// Weight tables in FRAGMENT ORDER: chunks of [64 lanes][8 bf16], one
// global_load_dwordx4 per wave = one contiguous 1 KB chunk.
#define OFF_ENCB  0u                    // 25000*128 bf16 = 6,400,000 B
#define OFF_W0SW  6400000u              // 128 chunks * 1KB
#define OFF_W1SW  6531072u              // 32 chunks * 1KB
#define OFF_W2SW  6563840u              // 32 chunks * 1KB
#define OFF_W3SW  6596608u              // 4 chunks * 1KB
#define WS_END    6600704u

// prep work partition (thread counts)
#define PR_ENCB4 800000
#define PR_W0SW  65536
#define PR_W1SW  16384
#define PR_W2SW  16384
#define PR_W3SW  2048
#define PR_COPY4 75000
#define PR_TOTAL (PR_ENCB4 + PR_W0SW + PR_W1SW + PR_W2SW + PR_W3SW + PR_COPY4)

__global__ __launch_bounds__(256) void prep_kernel(
    const float* __restrict__ encoded, const float* __restrict__ W0,
    const float* __restrict__ W1, const float* __restrict__ W2,
    const float* __restrict__ W3, const float* __restrict__ answer,
    bf16* __restrict__ encB, bf16* __restrict__ W0sw, bf16* __restrict__ W1sw,
    bf16* __restrict__ W2sw, bf16* __restrict__ W3sw, float* __restrict__ out)
{
    int idx = blockIdx.x * 256 + threadIdx.x;
    if (idx < PR_ENCB4) {               // float4 -> 4x bf16 (8 B store)
        float4 v = ((const float4*)encoded)[idx];
        bf16 pk[4] = {(bf16)v.x, (bf16)v.y, (bf16)v.z, (bf16)v.w};
        *(uint2*)(encB + idx * 4) = *(const uint2*)pk;
        return;
    }
    idx -= PR_ENCB4;
    if (idx < PR_W0SW) {
        int j = idx & 7, lane = (idx >> 3) & 63, c = idx >> 9;
        int fr = lane & 15, quad = lane >> 4;
        int kc = c & 15, iwv = c >> 4;
        int k = kc * 32 + quad * 8 + j;
        W0sw[idx] = (bf16)W0[k * 128 + iwv * 16 + fr];
        return;
    }
    idx -= PR_W0SW;
    if (idx < PR_W1SW) {
        int j = idx & 7, lane = (idx >> 3) & 63, c = idx >> 9;
        int fr = lane & 15, quad = lane >> 4;
        int kc = c & 3, nt = c >> 2;
        int k = kc * 32 + quad * 8 + j;
        W1sw[idx] = (bf16)W1[k * 128 + nt * 16 + fr];
        return;
    }
    idx -= PR_W1SW;
    if (idx < PR_W2SW) {
        int j = idx & 7, lane = (idx >> 3) & 63, c = idx >> 9;
        int fr = lane & 15, quad = lane >> 4;
        int kc = c & 3, nt = c >> 2;
        int k = kc * 32 + quad * 8 + j;
        W2sw[idx] = (bf16)W2[k * 128 + nt * 16 + fr];
        return;
    }
    idx -= PR_W2SW;
    if (idx < PR_W3SW) {
        int j = idx & 7, lane = (idx >> 3) & 63, kc = idx >> 9;
        int fr = lane & 15, quad = lane >> 4;
        int k = kc * 32 + quad * 8 + j;
        W3sw[idx] = (fr < 2) ? (bf16)W3[k * 2 + fr] : (bf16)0.0f;
        return;
    }
    idx -= PR_W3SW;
    if (idx < PR_COPY4) { ((float4*)out)[idx] = ((const float4*)answer)[idx]; }
}

// LDS ~19.7 KB (sA/sH aliased) + VGPR<=64 -> 8 blocks/CU (32 waves/CU)
__global__ __launch_bounds__(256, 8) void main_kernel(
    const float* __restrict__ coords, const int* __restrict__ propers,
    const float* __restrict__ tvec, const float* __restrict__ W0,
    const float* __restrict__ b0, const float* __restrict__ b1,
    const float* __restrict__ b2, const float* __restrict__ b3,
    const bf16* __restrict__ encB, const bf16* __restrict__ W0sw,
    const bf16* __restrict__ W1sw, const bf16* __restrict__ W2sw,
    const bf16* __restrict__ W3sw, float* __restrict__ out)
{
    // sA[16][520] (8320 elems) and sH[64][136] (8704 elems) have disjoint
    // live ranges: sA is dead after the phase-2 MFMA loop; sH is born in the
    // phase-2 epilogue (after a barrier). Alias them in one buffer.
    __shared__ bf16 sAH[8704];
    #define SA(p, c) sAH[(p) * 520 + (c)]
    #define SH(r, j) sAH[(r) * 136 + (j)]
    __shared__ int   sNodes[PB][4];
    __shared__ float sSn[ROWS], sCs[ROWS], sDl[ROWS], sDh[ROWS][3];
    __shared__ float sDelta[ROWS][2];

    const int tid  = threadIdx.x;
    const int pBase = blockIdx.x * PB;
    const float tv0 = tvec[0], tv1 = tvec[1], tv2 = tvec[2], tv3 = tvec[3];

    // ---- phase 1: stage sA (all) + geometry (tid<64); propers read direct ----
    {   // sA: 64 (p,i) rows of 256 B each; 4 threads per row (64B each)
        int pair = tid >> 2, sg = tid & 3;
        int p = pair >> 2, i = pair & 3;
        int node = propers[(pBase + p) * 4 + i];
        if (sg == 0) sNodes[p][i] = node;
        const uint4* src = (const uint4*)(encB + (size_t)node * 128 + sg * 32);
        uint4* dst = (uint4*)(&SA(p, i * 128 + sg * 32));
        #pragma unroll
        for (int q = 0; q < 4; ++q) dst[q] = src[q];
    }
    if (tid < ROWS) {
        int r = tid, p = r >> 2, t = r & 3;
        const int* prow = propers + (pBase + p) * 4;
        int n0 = prow[0], n1 = prow[1], n2 = prow[2], n3 = prow[3];
        const float* c0 = coords + n0 * 12 + t * 3;
        const float* c1 = coords + n1 * 12 + t * 3;
        const float* c2 = coords + n2 * 12 + t * 3;
        const float* c3 = coords + n3 * 12 + t * 3;
        float u1x = c1[0]-c0[0], u1y = c1[1]-c0[1], u1z = c1[2]-c0[2];
        float u2x = c2[0]-c1[0], u2y = c2[1]-c1[1], u2z = c2[2]-c1[2];
        float u3x = c3[0]-c2[0], u3y = c3[1]-c2[1], u3z = c3[2]-c2[2];
        float ax = u1y*u2z - u1z*u2y, ay = u1z*u2x - u1x*u2z, az = u1x*u2y - u1y*u2x;
        float bx = u2y*u3z - u2z*u3y, by = u2z*u3x - u2x*u3z, bz = u2x*u3y - u2y*u3x;
        float u2n = sqrtf(u2x*u2x + u2y*u2y + u2z*u2z);
        float num = u2n * (u1x*bx + u1y*by + u1z*bz);
        float den = ax*bx + ay*by + az*bz;
        float hyp = sqrtf(num*num + den*den);
        float sn, cs;
        if (hyp > 1e-30f) { float ih = 1.0f / hyp; sn = num * ih; cs = den * ih; }
        else { sn = 0.0f; cs = 1.0f; }
        float drx = c0[0]-c3[0], dry = c0[1]-c3[1], drz = c0[2]-c3[2];
        float dl = sqrtf(fmaxf(drx*drx + dry*dry + drz*drz, 1e-12f));
        float il = 1.0f / dl;
        sSn[r] = sn; sCs[r] = cs; sDl[r] = dl;
        sDh[r][0] = drx * il; sDh[r][1] = dry * il; sDh[r][2] = drz * il;
    }
    __syncthreads();

    const int wv = tid >> 6, lane = tid & 63;
    const int fr = lane & 15;      // free-dim index of A/B frags and C/D column
    const int quad = lane >> 4;

    // ---- phase 2: g-GEMM, M=16 propers, N=128, K=512; B-frags coalesced from W0sw ----
    f32x4 acc0 = {0.f,0.f,0.f,0.f}, acc1 = {0.f,0.f,0.f,0.f};
    {
        const bf16* aBase = &SA(fr, quad * 8);
        const bf16* w0b = W0sw + (size_t)(wv * 2) * 16 * 512 + lane * 8;
        #pragma unroll
        for (int kc = 0; kc < 16; ++kc) {
            bf16x8 aF = *(const bf16x8*)(aBase + kc * 32);
            bf16x8 bF0 = *(const bf16x8*)(w0b + kc * 512);
            bf16x8 bF1 = *(const bf16x8*)(w0b + (16 + kc) * 512);
            acc0 = __builtin_amdgcn_mfma_f32_16x16x32_bf16(aF, bF0, acc0, 0, 0, 0);
            acc1 = __builtin_amdgcn_mfma_f32_16x16x32_bf16(aF, bF1, acc1, 0, 0, 0);
        }
    }
    __syncthreads();   // sA reads complete before sH (aliased) writes begin

    // ---- h0: add rank-4 time/angle/length features + bias, leaky, write bf16 to sH ----
    #pragma unroll
    for (int i = 0; i < 2; ++i) {
        int j = (wv * 2 + i) * 16 + fr;                 // output column
        float w512 = W0[512 * 128 + j], w513 = W0[513 * 128 + j];
        float w514 = W0[514 * 128 + j], w515 = W0[515 * 128 + j];
        float bb = b0[j];
        const f32x4 acc = i ? acc1 : acc0;
        #pragma unroll
        for (int reg = 0; reg < 4; ++reg) {
            int p = quad * 4 + reg;                      // C/D row = proper index
            float g = acc[reg];
            #pragma unroll
            for (int t = 0; t < 4; ++t) {
                int r = p * 4 + t;
                float tvv = (t == 0) ? tv0 : (t == 1) ? tv1 : (t == 2) ? tv2 : tv3;
                float v = g + tvv * w512 + sSn[r] * w513 + sCs[r] * w514 + sDl[r] * w515 + bb;
                v = v > 0.0f ? v : LEAKY * v;
                SH(r, j) = (bf16)v;
            }
        }
    }
    __syncthreads();

    // ---- phase 3: h1 = leaky(h0 @ W1 + b1); B-frags coalesced from W1sw ----
    f32x4 hacc[8];
    #pragma unroll
    for (int nt = 0; nt < 8; ++nt) hacc[nt] = (f32x4){0.f,0.f,0.f,0.f};
    {
        const bf16* aRow = &SH(wv * 16 + fr, quad * 8);
        const bf16* w1b = W1sw + lane * 8;
        #pragma unroll
        for (int kc = 0; kc < 4; ++kc) {
            bf16x8 aF = *(const bf16x8*)(aRow + kc * 32);
            #pragma unroll
            for (int nt = 0; nt < 8; ++nt) {
                bf16x8 bF = *(const bf16x8*)(w1b + (nt * 4 + kc) * 512);
                hacc[nt] = __builtin_amdgcn_mfma_f32_16x16x32_bf16(aF, bF, hacc[nt], 0, 0, 0);
            }
        }
    }
    __syncthreads();   // all sH reads complete
    #pragma unroll
    for (int nt = 0; nt < 8; ++nt) {
        int j = nt * 16 + fr;
        float bb = b1[j];
        #pragma unroll
        for (int reg = 0; reg < 4; ++reg) {
            int r = wv * 16 + quad * 4 + reg;
            float v = hacc[nt][reg] + bb;
            v = v > 0.0f ? v : LEAKY * v;
            SH(r, j) = (bf16)v;
        }
    }
    __syncthreads();

    // ---- phase 4: h2 = leaky(h1 @ W2 + b2); B-frags coalesced from W2sw ----
    #pragma unroll
    for (int nt = 0; nt < 8; ++nt) hacc[nt] = (f32x4){0.f,0.f,0.f,0.f};
    {
        const bf16* aRow = &SH(wv * 16 + fr, quad * 8);
        const bf16* w2b = W2sw + lane * 8;
        #pragma unroll
        for (int kc = 0; kc < 4; ++kc) {
            bf16x8 aF = *(const bf16x8*)(aRow + kc * 32);
            #pragma unroll
            for (int nt = 0; nt < 8; ++nt) {
                bf16x8 bF = *(const bf16x8*)(w2b + (nt * 4 + kc) * 512);
                hacc[nt] = __builtin_amdgcn_mfma_f32_16x16x32_bf16(aF, bF, hacc[nt], 0, 0, 0);
            }
        }
    }
    __syncthreads();
    #pragma unroll
    for (int nt = 0; nt < 8; ++nt) {
        int j = nt * 16 + fr;
        float bb = b2[j];
        #pragma unroll
        for (int reg = 0; reg < 4; ++reg) {
            int r = wv * 16 + quad * 4 + reg;
            float v = hacc[nt][reg] + bb;
            v = v > 0.0f ? v : LEAKY * v;
            SH(r, j) = (bf16)v;
        }
    }
    __syncthreads();

    // ---- phase 5: delta = h2 @ W3 + b3 (W3 zero-padded to 16 cols) ----
    {
        f32x4 dacc = {0.f,0.f,0.f,0.f};
        const bf16* aRow = &SH(wv * 16 + fr, quad * 8);
        const bf16* w3b = W3sw + lane * 8;
        #pragma unroll
        for (int kc = 0; kc < 4; ++kc) {
            bf16x8 aF = *(const bf16x8*)(aRow + kc * 32);
            bf16x8 bF = *(const bf16x8*)(w3b + kc * 512);
            dacc = __builtin_amdgcn_mfma_f32_16x16x32_bf16(aF, bF, dacc, 0, 0, 0);
        }
        if (fr < 2) {
            float bb = b3[fr];
            #pragma unroll
            for (int reg = 0; reg < 4; ++reg)
                sDelta[wv * 16 + quad * 4 + reg][fr] = dacc[reg] + bb;
        }
    }
    __syncthreads();

    // ---- phase 6: scatter-add (6 atomics per row) ----
    for (int idx = tid; idx < ROWS * 6; idx += 256) {
        int r = idx / 6, c = idx % 6;
        int p = r >> 2, t = r & 3;
        int side = c / 3, ax = c % 3;
        int node = sNodes[p][side ? 3 : 0];
        float dval = side ? 0.5f * sDelta[r][1] : -0.5f * sDelta[r][0];
        atomicAdd(out + node * 12 + t * 3 + ax, dval * sDh[r][ax]);
    }
    #undef SA
    #undef SH
}

extern "C" void kernel_launch(void* const* d_in, const int* in_sizes, int n_in,
                              void* d_out, int out_size, void* d_ws, size_t ws_size,
                              hipStream_t stream) {
    const float* coords  = (const float*)d_in[0];
    const int*   propers = (const int*)d_in[1];
    const float* encoded = (const float*)d_in[2];
    const float* tvec    = (const float*)d_in[3];
    const float* answer  = (const float*)d_in[4];
    const float* W0 = (const float*)d_in[5];
    const float* b0 = (const float*)d_in[6];
    const float* W1 = (const float*)d_in[7];
    const float* b1 = (const float*)d_in[8];
    const float* W2 = (const float*)d_in[9];
    const float* b2 = (const float*)d_in[10];
    const float* W3 = (const float*)d_in[11];
    const float* b3 = (const float*)d_in[12];
    float* out = (float*)d_out;
    char* ws = (char*)d_ws;
    bf16* encB = (bf16*)(ws + OFF_ENCB);
    bf16* W0sw = (bf16*)(ws + OFF_W0SW);
    bf16* W1sw = (bf16*)(ws + OFF_W1SW);
    bf16* W2sw = (bf16*)(ws + OFF_W2SW);
    bf16* W3sw = (bf16*)(ws + OFF_W3SW);

    int prep_blocks = (PR_TOTAL + 255) / 256;
    prep_kernel<<<prep_blocks, 256, 0, stream>>>(encoded, W0, W1, W2, W3, answer,
                                                 encB, W0sw, W1sw, W2sw, W3sw, out);
    main_kernel<<<PP / PB, 256, 0, stream>>>(coords, propers, tvec, W0, b0, b1, b2, b3,
                                             encB, W0sw, W1sw, W2sw, W3sw, out);
}

// Round 5
// 232.774 us; speedup vs baseline: 1.0590x; 1.0590x over previous
//
#include <hip/hip_runtime.h>
#include <hip/hip_bf16.h>

// ---- problem constants ----
#define NN 25000
#define PP 100000
#define TT 4
#define DD 128
#define LEAKY 0.001f

#define PB 16          // propers per block
#define ROWS 64        // PB * TT rows of the MLP per block

typedef __bf16 bf16;
typedef __bf16 bf16x8 __attribute__((ext_vector_type(8)));
typedef float  f32x4  __attribute__((ext_vector_type(4)));

// ---- workspace layout (bytes) ----
// Weight tables in FRAGMENT ORDER: chunks of [64 lanes][8 bf16], one
// global_load_dwordx4 per wave = one contiguous 1 KB chunk.
#define OFF_ENCB  0u                    // 25000*128 bf16 = 6,400,000 B
#define OFF_W0SW  6400000u              // 128 chunks * 1KB
#define OFF_W1SW  6531072u              // 32 chunks * 1KB
#define OFF_W2SW  6563840u              // 32 chunks * 1KB
#define OFF_W3SW  6596608u              // 4 chunks * 1KB
#define WS_END    6600704u

// prep work partition (thread counts)
#define PR_ENCB4 800000
#define PR_W0SW  65536
#define PR_W1SW  16384
#define PR_W2SW  16384
#define PR_W3SW  2048
#define PR_COPY4 75000
#define PR_TOTAL (PR_ENCB4 + PR_W0SW + PR_W1SW + PR_W2SW + PR_W3SW + PR_COPY4)

__global__ __launch_bounds__(256) void prep_kernel(
    const float* __restrict__ encoded, const float* __restrict__ W0,
    const float* __restrict__ W1, const float* __restrict__ W2,
    const float* __restrict__ W3, const float* __restrict__ answer,
    bf16* __restrict__ encB, bf16* __restrict__ W0sw, bf16* __restrict__ W1sw,
    bf16* __restrict__ W2sw, bf16* __restrict__ W3sw, float* __restrict__ out)
{
    int idx = blockIdx.x * 256 + threadIdx.x;
    if (idx < PR_ENCB4) {               // float4 -> 4x bf16 (8 B store)
        float4 v = ((const float4*)encoded)[idx];
        bf16 pk[4] = {(bf16)v.x, (bf16)v.y, (bf16)v.z, (bf16)v.w};
        *(uint2*)(encB + idx * 4) = *(const uint2*)pk;
        return;
    }
    idx -= PR_ENCB4;
    if (idx < PR_W0SW) {
        int j = idx & 7, lane = (idx >> 3) & 63, c = idx >> 9;
        int fr = lane & 15, quad = lane >> 4;
        int kc = c & 15, iwv = c >> 4;
        int k = kc * 32 + quad * 8 + j;
        W0sw[idx] = (bf16)W0[k * 128 + iwv * 16 + fr];
        return;
    }
    idx -= PR_W0SW;
    if (idx < PR_W1SW) {
        int j = idx & 7, lane = (idx >> 3) & 63, c = idx >> 9;
        int fr = lane & 15, quad = lane >> 4;
        int kc = c & 3, nt = c >> 2;
        int k = kc * 32 + quad * 8 + j;
        W1sw[idx] = (bf16)W1[k * 128 + nt * 16 + fr];
        return;
    }
    idx -= PR_W1SW;
    if (idx < PR_W2SW) {
        int j = idx & 7, lane = (idx >> 3) & 63, c = idx >> 9;
        int fr = lane & 15, quad = lane >> 4;
        int kc = c & 3, nt = c >> 2;
        int k = kc * 32 + quad * 8 + j;
        W2sw[idx] = (bf16)W2[k * 128 + nt * 16 + fr];
        return;
    }
    idx -= PR_W2SW;
    if (idx < PR_W3SW) {
        int j = idx & 7, lane = (idx >> 3) & 63, kc = idx >> 9;
        int fr = lane & 15, quad = lane >> 4;
        int k = kc * 32 + quad * 8 + j;
        W3sw[idx] = (fr < 2) ? (bf16)W3[k * 2 + fr] : (bf16)0.0f;
        return;
    }
    idx -= PR_W3SW;
    if (idx < PR_COPY4) { ((float4*)out)[idx] = ((const float4*)answer)[idx]; }
}

// LDS ~19.7 KB (sA/sH aliased). launch_bounds(256,6) caps VGPR at ~85 so the
// allocator keeps its natural ~52 (NO spills — (256,8)'s 64-cap forced the
// 32-VGPR spill disaster of R4: +290 MB scratch traffic). At 52 VGPRs the HW
// still co-schedules 8 blocks/CU (LDS 19968*8 = 159.7 KB fits).
__global__ __launch_bounds__(256, 6) void main_kernel(
    const float* __restrict__ coords, const int* __restrict__ propers,
    const float* __restrict__ tvec, const float* __restrict__ W0,
    const float* __restrict__ b0, const float* __restrict__ b1,
    const float* __restrict__ b2, const float* __restrict__ b3,
    const bf16* __restrict__ encB, const bf16* __restrict__ W0sw,
    const bf16* __restrict__ W1sw, const bf16* __restrict__ W2sw,
    const bf16* __restrict__ W3sw, float* __restrict__ out)
{
    // sA[16][520] (8320 elems) and sH[64][136] (8704 elems) have disjoint
    // live ranges: sA is dead after the phase-2 MFMA loop; sH is born in the
    // phase-2 epilogue (after a barrier). Alias them in one buffer.
    __shared__ bf16 sAH[8704];
    #define SA(p, c) sAH[(p) * 520 + (c)]
    #define SH(r, j) sAH[(r) * 136 + (j)]
    __shared__ int   sNodes[PB][4];
    __shared__ float sSn[ROWS], sCs[ROWS], sDl[ROWS], sDh[ROWS][3];
    __shared__ float sDelta[ROWS][2];

    const int tid  = threadIdx.x;
    const int pBase = blockIdx.x * PB;
    const float tv0 = tvec[0], tv1 = tvec[1], tv2 = tvec[2], tv3 = tvec[3];

    // ---- phase 1: stage sA (all) + geometry (tid<64); propers read direct ----
    {   // sA: 64 (p,i) rows of 256 B each; 4 threads per row (64B each)
        int pair = tid >> 2, sg = tid & 3;
        int p = pair >> 2, i = pair & 3;
        int node = propers[(pBase + p) * 4 + i];
        if (sg == 0) sNodes[p][i] = node;
        const uint4* src = (const uint4*)(encB + (size_t)node * 128 + sg * 32);
        uint4* dst = (uint4*)(&SA(p, i * 128 + sg * 32));
        #pragma unroll
        for (int q = 0; q < 4; ++q) dst[q] = src[q];
    }
    if (tid < ROWS) {
        int r = tid, p = r >> 2, t = r & 3;
        const int* prow = propers + (pBase + p) * 4;
        int n0 = prow[0], n1 = prow[1], n2 = prow[2], n3 = prow[3];
        const float* c0 = coords + n0 * 12 + t * 3;
        const float* c1 = coords + n1 * 12 + t * 3;
        const float* c2 = coords + n2 * 12 + t * 3;
        const float* c3 = coords + n3 * 12 + t * 3;
        float u1x = c1[0]-c0[0], u1y = c1[1]-c0[1], u1z = c1[2]-c0[2];
        float u2x = c2[0]-c1[0], u2y = c2[1]-c1[1], u2z = c2[2]-c1[2];
        float u3x = c3[0]-c2[0], u3y = c3[1]-c2[1], u3z = c3[2]-c2[2];
        float ax = u1y*u2z - u1z*u2y, ay = u1z*u2x - u1x*u2z, az = u1x*u2y - u1y*u2x;
        float bx = u2y*u3z - u2z*u3y, by = u2z*u3x - u2x*u3z, bz = u2x*u3y - u2y*u3x;
        float u2n = sqrtf(u2x*u2x + u2y*u2y + u2z*u2z);
        float num = u2n * (u1x*bx + u1y*by + u1z*bz);
        float den = ax*bx + ay*by + az*bz;
        float hyp = sqrtf(num*num + den*den);
        float sn, cs;
        if (hyp > 1e-30f) { float ih = 1.0f / hyp; sn = num * ih; cs = den * ih; }
        else { sn = 0.0f; cs = 1.0f; }
        float drx = c0[0]-c3[0], dry = c0[1]-c3[1], drz = c0[2]-c3[2];
        float dl = sqrtf(fmaxf(drx*drx + dry*dry + drz*drz, 1e-12f));
        float il = 1.0f / dl;
        sSn[r] = sn; sCs[r] = cs; sDl[r] = dl;
        sDh[r][0] = drx * il; sDh[r][1] = dry * il; sDh[r][2] = drz * il;
    }
    __syncthreads();

    const int wv = tid >> 6, lane = tid & 63;
    const int fr = lane & 15;      // free-dim index of A/B frags and C/D column
    const int quad = lane >> 4;

    // ---- phase 2: g-GEMM, M=16 propers, N=128, K=512; B-frags coalesced from W0sw ----
    f32x4 acc0 = {0.f,0.f,0.f,0.f}, acc1 = {0.f,0.f,0.f,0.f};
    {
        const bf16* aBase = &SA(fr, quad * 8);
        const bf16* w0b = W0sw + (size_t)(wv * 2) * 16 * 512 + lane * 8;
        #pragma unroll
        for (int kc = 0; kc < 16; ++kc) {
            bf16x8 aF = *(const bf16x8*)(aBase + kc * 32);
            bf16x8 bF0 = *(const bf16x8*)(w0b + kc * 512);
            bf16x8 bF1 = *(const bf16x8*)(w0b + (16 + kc) * 512);
            acc0 = __builtin_amdgcn_mfma_f32_16x16x32_bf16(aF, bF0, acc0, 0, 0, 0);
            acc1 = __builtin_amdgcn_mfma_f32_16x16x32_bf16(aF, bF1, acc1, 0, 0, 0);
        }
    }
    __syncthreads();   // sA reads complete before sH (aliased) writes begin

    // ---- h0: add rank-4 time/angle/length features + bias, leaky, write bf16 to sH ----
    #pragma unroll
    for (int i = 0; i < 2; ++i) {
        int j = (wv * 2 + i) * 16 + fr;                 // output column
        float w512 = W0[512 * 128 + j], w513 = W0[513 * 128 + j];
        float w514 = W0[514 * 128 + j], w515 = W0[515 * 128 + j];
        float bb = b0[j];
        const f32x4 acc = i ? acc1 : acc0;
        #pragma unroll
        for (int reg = 0; reg < 4; ++reg) {
            int p = quad * 4 + reg;                      // C/D row = proper index
            float g = acc[reg];
            #pragma unroll
            for (int t = 0; t < 4; ++t) {
                int r = p * 4 + t;
                float tvv = (t == 0) ? tv0 : (t == 1) ? tv1 : (t == 2) ? tv2 : tv3;
                float v = g + tvv * w512 + sSn[r] * w513 + sCs[r] * w514 + sDl[r] * w515 + bb;
                v = v > 0.0f ? v : LEAKY * v;
                SH(r, j) = (bf16)v;
            }
        }
    }
    __syncthreads();

    // ---- phase 3: h1 = leaky(h0 @ W1 + b1); B-frags coalesced from W1sw ----
    f32x4 hacc[8];
    #pragma unroll
    for (int nt = 0; nt < 8; ++nt) hacc[nt] = (f32x4){0.f,0.f,0.f,0.f};
    {
        const bf16* aRow = &SH(wv * 16 + fr, quad * 8);
        const bf16* w1b = W1sw + lane * 8;
        #pragma unroll
        for (int kc = 0; kc < 4; ++kc) {
            bf16x8 aF = *(const bf16x8*)(aRow + kc * 32);
            #pragma unroll
            for (int nt = 0; nt < 8; ++nt) {
                bf16x8 bF = *(const bf16x8*)(w1b + (nt * 4 + kc) * 512);
                hacc[nt] = __builtin_amdgcn_mfma_f32_16x16x32_bf16(aF, bF, hacc[nt], 0, 0, 0);
            }
        }
    }
    __syncthreads();   // all sH reads complete
    #pragma unroll
    for (int nt = 0; nt < 8; ++nt) {
        int j = nt * 16 + fr;
        float bb = b1[j];
        #pragma unroll
        for (int reg = 0; reg < 4; ++reg) {
            int r = wv * 16 + quad * 4 + reg;
            float v = hacc[nt][reg] + bb;
            v = v > 0.0f ? v : LEAKY * v;
            SH(r, j) = (bf16)v;
        }
    }
    __syncthreads();

    // ---- phase 4: h2 = leaky(h1 @ W2 + b2); B-frags coalesced from W2sw ----
    #pragma unroll
    for (int nt = 0; nt < 8; ++nt) hacc[nt] = (f32x4){0.f,0.f,0.f,0.f};
    {
        const bf16* aRow = &SH(wv * 16 + fr, quad * 8);
        const bf16* w2b = W2sw + lane * 8;
        #pragma unroll
        for (int kc = 0; kc < 4; ++kc) {
            bf16x8 aF = *(const bf16x8*)(aRow + kc * 32);
            #pragma unroll
            for (int nt = 0; nt < 8; ++nt) {
                bf16x8 bF = *(const bf16x8*)(w2b + (nt * 4 + kc) * 512);
                hacc[nt] = __builtin_amdgcn_mfma_f32_16x16x32_bf16(aF, bF, hacc[nt], 0, 0, 0);
            }
        }
    }
    __syncthreads();
    #pragma unroll
    for (int nt = 0; nt < 8; ++nt) {
        int j = nt * 16 + fr;
        float bb = b2[j];
        #pragma unroll
        for (int reg = 0; reg < 4; ++reg) {
            int r = wv * 16 + quad * 4 + reg;
            float v = hacc[nt][reg] + bb;
            v = v > 0.0f ? v : LEAKY * v;
            SH(r, j) = (bf16)v;
        }
    }
    __syncthreads();

    // ---- phase 5: delta = h2 @ W3 + b3 (W3 zero-padded to 16 cols) ----
    {
        f32x4 dacc = {0.f,0.f,0.f,0.f};
        const bf16* aRow = &SH(wv * 16 + fr, quad * 8);
        const bf16* w3b = W3sw + lane * 8;
        #pragma unroll
        for (int kc = 0; kc < 4; ++kc) {
            bf16x8 aF = *(const bf16x8*)(aRow + kc * 32);
            bf16x8 bF = *(const bf16x8*)(w3b + kc * 512);
            dacc = __builtin_amdgcn_mfma_f32_16x16x32_bf16(aF, bF, dacc, 0, 0, 0);
        }
        if (fr < 2) {
            float bb = b3[fr];
            #pragma unroll
            for (int reg = 0; reg < 4; ++reg)
                sDelta[wv * 16 + quad * 4 + reg][fr] = dacc[reg] + bb;
        }
    }
    __syncthreads();

    // ---- phase 6: scatter-add (6 atomics per row) ----
    for (int idx = tid; idx < ROWS * 6; idx += 256) {
        int r = idx / 6, c = idx % 6;
        int p = r >> 2, t = r & 3;
        int side = c / 3, ax = c % 3;
        int node = sNodes[p][side ? 3 : 0];
        float dval = side ? 0.5f * sDelta[r][1] : -0.5f * sDelta[r][0];
        atomicAdd(out + node * 12 + t * 3 + ax, dval * sDh[r][ax]);
    }
    #undef SA
    #undef SH
}

extern "C" void kernel_launch(void* const* d_in, const int* in_sizes, int n_in,
                              void* d_out, int out_size, void* d_ws, size_t ws_size,
                              hipStream_t stream) {
    const float* coords  = (const float*)d_in[0];
    const int*   propers = (const int*)d_in[1];
    const float* encoded = (const float*)d_in[2];
    const float* tvec    = (const float*)d_in[3];
    const float* answer  = (const float*)d_in[4];
    const float* W0 = (const float*)d_in[5];
    const float* b0 = (const float*)d_in[6];
    const float* W1 = (const float*)d_in[7];
    const float* b1 = (const float*)d_in[8];
    const float* W2 = (const float*)d_in[9];
    const float* b2 = (const float*)d_in[10];
    const float* W3 = (const float*)d_in[11];
    const float* b3 = (const float*)d_in[12];
    float* out = (float*)d_out;
    char* ws = (char*)d_ws;
    bf16* encB = (bf16*)(ws + OFF_ENCB);
    bf16* W0sw = (bf16*)(ws + OFF_W0SW);
    bf16* W1sw = (bf16*)(ws + OFF_W1SW);
    bf16* W2sw = (bf16*)(ws + OFF_W2SW);
    bf16* W3sw = (bf16*)(ws + OFF_W3SW);

    int prep_blocks = (PR_TOTAL + 255) / 256;
    prep_kernel<<<prep_blocks, 256, 0, stream>>>(encoded, W0, W1, W2, W3, answer,
                                                 encB, W0sw, W1sw, W2sw, W3sw, out);
    main_kernel<<<PP / PB, 256, 0, stream>>>(coords, propers, tvec, W0, b0, b1, b2, b3,
                                             encB, W0sw, W1sw, W2sw, W3sw, out);
}

// Round 6
// 203.494 us; speedup vs baseline: 1.2114x; 1.1439x over previous
//
#include <hip/hip_runtime.h>
#include <hip/hip_bf16.h>

// ---- problem constants ----
#define NN 25000
#define PP 100000
#define TT 4
#define DD 128
#define LEAKY 0.001f

#define PB 16          // propers per block
#define ROWS 64        // PB * TT rows of the MLP per block

typedef __bf16 bf16;
typedef __bf16 bf16x8 __attribute__((ext_vector_type(8)));
typedef float  f32x4  __attribute__((ext_vector_type(4)));

// ---- workspace layout (bytes) ----
// Weight tables in FRAGMENT ORDER: chunks of [64 lanes][8 bf16], one
// global_load_dwordx4 per wave = one contiguous 1 KB chunk.
#define OFF_ENCB  0u                    // 25000*128 bf16 = 6,400,000 B
#define OFF_W0SW  6400000u              // 128 chunks * 1KB
#define OFF_W1SW  6531072u              // 32 chunks * 1KB
#define OFF_W2SW  6563840u              // 32 chunks * 1KB
#define OFF_W3SW  6596608u              // 4 chunks * 1KB
#define WS_END    6600704u

// prep work partition (thread counts)
#define PR_ENCB4 800000
#define PR_W0SW  65536
#define PR_W1SW  16384
#define PR_W2SW  16384
#define PR_W3SW  2048
#define PR_COPY4 75000
#define PR_TOTAL (PR_ENCB4 + PR_W0SW + PR_W1SW + PR_W2SW + PR_W3SW + PR_COPY4)

__global__ __launch_bounds__(256) void prep_kernel(
    const float* __restrict__ encoded, const float* __restrict__ W0,
    const float* __restrict__ W1, const float* __restrict__ W2,
    const float* __restrict__ W3, const float* __restrict__ answer,
    bf16* __restrict__ encB, bf16* __restrict__ W0sw, bf16* __restrict__ W1sw,
    bf16* __restrict__ W2sw, bf16* __restrict__ W3sw, float* __restrict__ out)
{
    int idx = blockIdx.x * 256 + threadIdx.x;
    if (idx < PR_ENCB4) {               // float4 -> 4x bf16 (8 B store)
        float4 v = ((const float4*)encoded)[idx];
        bf16 pk[4] = {(bf16)v.x, (bf16)v.y, (bf16)v.z, (bf16)v.w};
        *(uint2*)(encB + idx * 4) = *(const uint2*)pk;
        return;
    }
    idx -= PR_ENCB4;
    if (idx < PR_W0SW) {
        int j = idx & 7, lane = (idx >> 3) & 63, c = idx >> 9;
        int fr = lane & 15, quad = lane >> 4;
        int kc = c & 15, iwv = c >> 4;
        int k = kc * 32 + quad * 8 + j;
        W0sw[idx] = (bf16)W0[k * 128 + iwv * 16 + fr];
        return;
    }
    idx -= PR_W0SW;
    if (idx < PR_W1SW) {
        int j = idx & 7, lane = (idx >> 3) & 63, c = idx >> 9;
        int fr = lane & 15, quad = lane >> 4;
        int kc = c & 3, nt = c >> 2;
        int k = kc * 32 + quad * 8 + j;
        W1sw[idx] = (bf16)W1[k * 128 + nt * 16 + fr];
        return;
    }
    idx -= PR_W1SW;
    if (idx < PR_W2SW) {
        int j = idx & 7, lane = (idx >> 3) & 63, c = idx >> 9;
        int fr = lane & 15, quad = lane >> 4;
        int kc = c & 3, nt = c >> 2;
        int k = kc * 32 + quad * 8 + j;
        W2sw[idx] = (bf16)W2[k * 128 + nt * 16 + fr];
        return;
    }
    idx -= PR_W2SW;
    if (idx < PR_W3SW) {
        int j = idx & 7, lane = (idx >> 3) & 63, kc = idx >> 9;
        int fr = lane & 15, quad = lane >> 4;
        int k = kc * 32 + quad * 8 + j;
        W3sw[idx] = (fr < 2) ? (bf16)W3[k * 2 + fr] : (bf16)0.0f;
        return;
    }
    idx -= PR_W3SW;
    if (idx < PR_COPY4) { ((float4*)out)[idx] = ((const float4*)answer)[idx]; }
}

// LDS ~19.7 KB (sA/sH aliased). __launch_bounds__(256,4): guarantee-only hint.
// Measured series: min-waves 4 -> 52 VGPR no spill; 6 -> 40 VGPR spill (+150MB
// scratch); 8 -> 32 VGPR spill (+290MB). The allocator squeezes below natural
// demand for any min-waves > 4, so we request 4 and let the HW co-schedule
// 8 blocks/CU on its own (52 regs <= 64-reg bin for 8 waves/SIMD; LDS
// 19968*8 = 159.7 KB <= 160 KB).
__global__ __launch_bounds__(256, 4) void main_kernel(
    const float* __restrict__ coords, const int* __restrict__ propers,
    const float* __restrict__ tvec, const float* __restrict__ W0,
    const float* __restrict__ b0, const float* __restrict__ b1,
    const float* __restrict__ b2, const float* __restrict__ b3,
    const bf16* __restrict__ encB, const bf16* __restrict__ W0sw,
    const bf16* __restrict__ W1sw, const bf16* __restrict__ W2sw,
    const bf16* __restrict__ W3sw, float* __restrict__ out)
{
    // sA[16][520] (8320 elems) and sH[64][136] (8704 elems) have disjoint
    // live ranges: sA is dead after the phase-2 MFMA loop; sH is born in the
    // phase-2 epilogue (after a barrier). Alias them in one buffer.
    __shared__ bf16 sAH[8704];
    #define SA(p, c) sAH[(p) * 520 + (c)]
    #define SH(r, j) sAH[(r) * 136 + (j)]
    __shared__ int   sNodes[PB][4];
    __shared__ float sSn[ROWS], sCs[ROWS], sDl[ROWS], sDh[ROWS][3];
    __shared__ float sDelta[ROWS][2];

    const int tid  = threadIdx.x;
    const int pBase = blockIdx.x * PB;
    const float tv0 = tvec[0], tv1 = tvec[1], tv2 = tvec[2], tv3 = tvec[3];

    // ---- phase 1: stage sA (all) + geometry (tid<64); propers read direct ----
    {   // sA: 64 (p,i) rows of 256 B each; 4 threads per row (64B each)
        int pair = tid >> 2, sg = tid & 3;
        int p = pair >> 2, i = pair & 3;
        int node = propers[(pBase + p) * 4 + i];
        if (sg == 0) sNodes[p][i] = node;
        const uint4* src = (const uint4*)(encB + (size_t)node * 128 + sg * 32);
        uint4* dst = (uint4*)(&SA(p, i * 128 + sg * 32));
        #pragma unroll
        for (int q = 0; q < 4; ++q) dst[q] = src[q];
    }
    if (tid < ROWS) {
        int r = tid, p = r >> 2, t = r & 3;
        const int* prow = propers + (pBase + p) * 4;
        int n0 = prow[0], n1 = prow[1], n2 = prow[2], n3 = prow[3];
        const float* c0 = coords + n0 * 12 + t * 3;
        const float* c1 = coords + n1 * 12 + t * 3;
        const float* c2 = coords + n2 * 12 + t * 3;
        const float* c3 = coords + n3 * 12 + t * 3;
        float u1x = c1[0]-c0[0], u1y = c1[1]-c0[1], u1z = c1[2]-c0[2];
        float u2x = c2[0]-c1[0], u2y = c2[1]-c1[1], u2z = c2[2]-c1[2];
        float u3x = c3[0]-c2[0], u3y = c3[1]-c2[1], u3z = c3[2]-c2[2];
        float ax = u1y*u2z - u1z*u2y, ay = u1z*u2x - u1x*u2z, az = u1x*u2y - u1y*u2x;
        float bx = u2y*u3z - u2z*u3y, by = u2z*u3x - u2x*u3z, bz = u2x*u3y - u2y*u3x;
        float u2n = sqrtf(u2x*u2x + u2y*u2y + u2z*u2z);
        float num = u2n * (u1x*bx + u1y*by + u1z*bz);
        float den = ax*bx + ay*by + az*bz;
        float hyp = sqrtf(num*num + den*den);
        float sn, cs;
        if (hyp > 1e-30f) { float ih = 1.0f / hyp; sn = num * ih; cs = den * ih; }
        else { sn = 0.0f; cs = 1.0f; }
        float drx = c0[0]-c3[0], dry = c0[1]-c3[1], drz = c0[2]-c3[2];
        float dl = sqrtf(fmaxf(drx*drx + dry*dry + drz*drz, 1e-12f));
        float il = 1.0f / dl;
        sSn[r] = sn; sCs[r] = cs; sDl[r] = dl;
        sDh[r][0] = drx * il; sDh[r][1] = dry * il; sDh[r][2] = drz * il;
    }
    __syncthreads();

    const int wv = tid >> 6, lane = tid & 63;
    const int fr = lane & 15;      // free-dim index of A/B frags and C/D column
    const int quad = lane >> 4;

    // ---- phase 2: g-GEMM, M=16 propers, N=128, K=512; B-frags coalesced from W0sw ----
    f32x4 acc0 = {0.f,0.f,0.f,0.f}, acc1 = {0.f,0.f,0.f,0.f};
    {
        const bf16* aBase = &SA(fr, quad * 8);
        const bf16* w0b = W0sw + (size_t)(wv * 2) * 16 * 512 + lane * 8;
        #pragma unroll
        for (int kc = 0; kc < 16; ++kc) {
            bf16x8 aF = *(const bf16x8*)(aBase + kc * 32);
            bf16x8 bF0 = *(const bf16x8*)(w0b + kc * 512);
            bf16x8 bF1 = *(const bf16x8*)(w0b + (16 + kc) * 512);
            acc0 = __builtin_amdgcn_mfma_f32_16x16x32_bf16(aF, bF0, acc0, 0, 0, 0);
            acc1 = __builtin_amdgcn_mfma_f32_16x16x32_bf16(aF, bF1, acc1, 0, 0, 0);
        }
    }
    __syncthreads();   // sA reads complete before sH (aliased) writes begin

    // ---- h0: add rank-4 time/angle/length features + bias, leaky, write bf16 to sH ----
    #pragma unroll
    for (int i = 0; i < 2; ++i) {
        int j = (wv * 2 + i) * 16 + fr;                 // output column
        float w512 = W0[512 * 128 + j], w513 = W0[513 * 128 + j];
        float w514 = W0[514 * 128 + j], w515 = W0[515 * 128 + j];
        float bb = b0[j];
        const f32x4 acc = i ? acc1 : acc0;
        #pragma unroll
        for (int reg = 0; reg < 4; ++reg) {
            int p = quad * 4 + reg;                      // C/D row = proper index
            float g = acc[reg];
            #pragma unroll
            for (int t = 0; t < 4; ++t) {
                int r = p * 4 + t;
                float tvv = (t == 0) ? tv0 : (t == 1) ? tv1 : (t == 2) ? tv2 : tv3;
                float v = g + tvv * w512 + sSn[r] * w513 + sCs[r] * w514 + sDl[r] * w515 + bb;
                v = v > 0.0f ? v : LEAKY * v;
                SH(r, j) = (bf16)v;
            }
        }
    }
    __syncthreads();

    // ---- phase 3: h1 = leaky(h0 @ W1 + b1); B-frags coalesced from W1sw ----
    f32x4 hacc[8];
    #pragma unroll
    for (int nt = 0; nt < 8; ++nt) hacc[nt] = (f32x4){0.f,0.f,0.f,0.f};
    {
        const bf16* aRow = &SH(wv * 16 + fr, quad * 8);
        const bf16* w1b = W1sw + lane * 8;
        #pragma unroll
        for (int kc = 0; kc < 4; ++kc) {
            bf16x8 aF = *(const bf16x8*)(aRow + kc * 32);
            #pragma unroll
            for (int nt = 0; nt < 8; ++nt) {
                bf16x8 bF = *(const bf16x8*)(w1b + (nt * 4 + kc) * 512);
                hacc[nt] = __builtin_amdgcn_mfma_f32_16x16x32_bf16(aF, bF, hacc[nt], 0, 0, 0);
            }
        }
    }
    __syncthreads();   // all sH reads complete
    #pragma unroll
    for (int nt = 0; nt < 8; ++nt) {
        int j = nt * 16 + fr;
        float bb = b1[j];
        #pragma unroll
        for (int reg = 0; reg < 4; ++reg) {
            int r = wv * 16 + quad * 4 + reg;
            float v = hacc[nt][reg] + bb;
            v = v > 0.0f ? v : LEAKY * v;
            SH(r, j) = (bf16)v;
        }
    }
    __syncthreads();

    // ---- phase 4: h2 = leaky(h1 @ W2 + b2); B-frags coalesced from W2sw ----
    #pragma unroll
    for (int nt = 0; nt < 8; ++nt) hacc[nt] = (f32x4){0.f,0.f,0.f,0.f};
    {
        const bf16* aRow = &SH(wv * 16 + fr, quad * 8);
        const bf16* w2b = W2sw + lane * 8;
        #pragma unroll
        for (int kc = 0; kc < 4; ++kc) {
            bf16x8 aF = *(const bf16x8*)(aRow + kc * 32);
            #pragma unroll
            for (int nt = 0; nt < 8; ++nt) {
                bf16x8 bF = *(const bf16x8*)(w2b + (nt * 4 + kc) * 512);
                hacc[nt] = __builtin_amdgcn_mfma_f32_16x16x32_bf16(aF, bF, hacc[nt], 0, 0, 0);
            }
        }
    }
    __syncthreads();
    #pragma unroll
    for (int nt = 0; nt < 8; ++nt) {
        int j = nt * 16 + fr;
        float bb = b2[j];
        #pragma unroll
        for (int reg = 0; reg < 4; ++reg) {
            int r = wv * 16 + quad * 4 + reg;
            float v = hacc[nt][reg] + bb;
            v = v > 0.0f ? v : LEAKY * v;
            SH(r, j) = (bf16)v;
        }
    }
    __syncthreads();

    // ---- phase 5: delta = h2 @ W3 + b3 (W3 zero-padded to 16 cols) ----
    {
        f32x4 dacc = {0.f,0.f,0.f,0.f};
        const bf16* aRow = &SH(wv * 16 + fr, quad * 8);
        const bf16* w3b = W3sw + lane * 8;
        #pragma unroll
        for (int kc = 0; kc < 4; ++kc) {
            bf16x8 aF = *(const bf16x8*)(aRow + kc * 32);
            bf16x8 bF = *(const bf16x8*)(w3b + kc * 512);
            dacc = __builtin_amdgcn_mfma_f32_16x16x32_bf16(aF, bF, dacc, 0, 0, 0);
        }
        if (fr < 2) {
            float bb = b3[fr];
            #pragma unroll
            for (int reg = 0; reg < 4; ++reg)
                sDelta[wv * 16 + quad * 4 + reg][fr] = dacc[reg] + bb;
        }
    }
    __syncthreads();

    // ---- phase 6: scatter-add (6 atomics per row) ----
    for (int idx = tid; idx < ROWS * 6; idx += 256) {
        int r = idx / 6, c = idx % 6;
        int p = r >> 2, t = r & 3;
        int side = c / 3, ax = c % 3;
        int node = sNodes[p][side ? 3 : 0];
        float dval = side ? 0.5f * sDelta[r][1] : -0.5f * sDelta[r][0];
        atomicAdd(out + node * 12 + t * 3 + ax, dval * sDh[r][ax]);
    }
    #undef SA
    #undef SH
}

extern "C" void kernel_launch(void* const* d_in, const int* in_sizes, int n_in,
                              void* d_out, int out_size, void* d_ws, size_t ws_size,
                              hipStream_t stream) {
    const float* coords  = (const float*)d_in[0];
    const int*   propers = (const int*)d_in[1];
    const float* encoded = (const float*)d_in[2];
    const float* tvec    = (const float*)d_in[3];
    const float* answer  = (const float*)d_in[4];
    const float* W0 = (const float*)d_in[5];
    const float* b0 = (const float*)d_in[6];
    const float* W1 = (const float*)d_in[7];
    const float* b1 = (const float*)d_in[8];
    const float* W2 = (const float*)d_in[9];
    const float* b2 = (const float*)d_in[10];
    const float* W3 = (const float*)d_in[11];
    const float* b3 = (const float*)d_in[12];
    float* out = (float*)d_out;
    char* ws = (char*)d_ws;
    bf16* encB = (bf16*)(ws + OFF_ENCB);
    bf16* W0sw = (bf16*)(ws + OFF_W0SW);
    bf16* W1sw = (bf16*)(ws + OFF_W1SW);
    bf16* W2sw = (bf16*)(ws + OFF_W2SW);
    bf16* W3sw = (bf16*)(ws + OFF_W3SW);

    int prep_blocks = (PR_TOTAL + 255) / 256;
    prep_kernel<<<prep_blocks, 256, 0, stream>>>(encoded, W0, W1, W2, W3, answer,
                                                 encB, W0sw, W1sw, W2sw, W3sw, out);
    main_kernel<<<PP / PB, 256, 0, stream>>>(coords, propers, tvec, W0, b0, b1, b2, b3,
                                             encB, W0sw, W1sw, W2sw, W3sw, out);
}

// Round 7
// 197.641 us; speedup vs baseline: 1.2473x; 1.0296x over previous
//
#include <hip/hip_runtime.h>
#include <hip/hip_bf16.h>

// ---- problem constants ----
#define NN 25000
#define PP 100000
#define TT 4
#define DD 128
#define LEAKY 0.001f

#define PB 16          // propers per block
#define ROWS 64        // PB * TT rows of the MLP per block

typedef __bf16 bf16;
typedef __bf16 bf16x8 __attribute__((ext_vector_type(8)));
typedef float  f32x4  __attribute__((ext_vector_type(4)));

// ---- workspace layout (bytes) ----
// Weight tables in FRAGMENT ORDER: chunks of [64 lanes][8 bf16], one
// global_load_dwordx4 per wave = one contiguous 1 KB chunk.
#define OFF_ENCB  0u                    // 25000*128 bf16 = 6,400,000 B
#define OFF_W0SW  6400000u              // 128 chunks * 1KB
#define OFF_W1SW  6531072u              // 32 chunks * 1KB
#define OFF_W2SW  6563840u              // 32 chunks * 1KB
#define OFF_W3SW  6596608u              // 4 chunks * 1KB
#define WS_END    6600704u

// prep work partition (thread counts)
#define PR_ENCB4 800000
#define PR_W0SW  65536
#define PR_W1SW  16384
#define PR_W2SW  16384
#define PR_W3SW  2048
#define PR_COPY4 75000
#define PR_TOTAL (PR_ENCB4 + PR_W0SW + PR_W1SW + PR_W2SW + PR_W3SW + PR_COPY4)

__global__ __launch_bounds__(256) void prep_kernel(
    const float* __restrict__ encoded, const float* __restrict__ W0,
    const float* __restrict__ W1, const float* __restrict__ W2,
    const float* __restrict__ W3, const float* __restrict__ answer,
    bf16* __restrict__ encB, bf16* __restrict__ W0sw, bf16* __restrict__ W1sw,
    bf16* __restrict__ W2sw, bf16* __restrict__ W3sw, float* __restrict__ out)
{
    int idx = blockIdx.x * 256 + threadIdx.x;
    if (idx < PR_ENCB4) {               // float4 -> 4x bf16 (8 B store)
        float4 v = ((const float4*)encoded)[idx];
        bf16 pk[4] = {(bf16)v.x, (bf16)v.y, (bf16)v.z, (bf16)v.w};
        *(uint2*)(encB + idx * 4) = *(const uint2*)pk;
        return;
    }
    idx -= PR_ENCB4;
    if (idx < PR_W0SW) {
        int j = idx & 7, lane = (idx >> 3) & 63, c = idx >> 9;
        int fr = lane & 15, quad = lane >> 4;
        int kc = c & 15, iwv = c >> 4;
        int k = kc * 32 + quad * 8 + j;
        W0sw[idx] = (bf16)W0[k * 128 + iwv * 16 + fr];
        return;
    }
    idx -= PR_W0SW;
    if (idx < PR_W1SW) {
        int j = idx & 7, lane = (idx >> 3) & 63, c = idx >> 9;
        int fr = lane & 15, quad = lane >> 4;
        int kc = c & 3, nt = c >> 2;
        int k = kc * 32 + quad * 8 + j;
        W1sw[idx] = (bf16)W1[k * 128 + nt * 16 + fr];
        return;
    }
    idx -= PR_W1SW;
    if (idx < PR_W2SW) {
        int j = idx & 7, lane = (idx >> 3) & 63, c = idx >> 9;
        int fr = lane & 15, quad = lane >> 4;
        int kc = c & 3, nt = c >> 2;
        int k = kc * 32 + quad * 8 + j;
        W2sw[idx] = (bf16)W2[k * 128 + nt * 16 + fr];
        return;
    }
    idx -= PR_W2SW;
    if (idx < PR_W3SW) {
        int j = idx & 7, lane = (idx >> 3) & 63, kc = idx >> 9;
        int fr = lane & 15, quad = lane >> 4;
        int k = kc * 32 + quad * 8 + j;
        W3sw[idx] = (fr < 2) ? (bf16)W3[k * 2 + fr] : (bf16)0.0f;
        return;
    }
    idx -= PR_W3SW;
    if (idx < PR_COPY4) { ((float4*)out)[idx] = ((const float4*)answer)[idx]; }
}

// 512 threads = 8 waves; each wave owns a 16-row x 16/64-col quadrant so only
// hacc[4] accumulators are live -> per-wave demand ~50 regs, fitting the
// 64-reg budget of (512,8): 8 waves/SIMD = 4 blocks/CU = 32 waves/CU without
// spills. (Measured allocator model: it consumes the full budget implied by
// the min-waves request and spills if natural demand exceeds it — R4/R5.)
__global__ __launch_bounds__(512, 8) void main_kernel(
    const float* __restrict__ coords, const int* __restrict__ propers,
    const float* __restrict__ tvec, const float* __restrict__ W0,
    const float* __restrict__ b0, const float* __restrict__ b1,
    const float* __restrict__ b2, const float* __restrict__ b3,
    const bf16* __restrict__ encB, const bf16* __restrict__ W0sw,
    const bf16* __restrict__ W1sw, const bf16* __restrict__ W2sw,
    const bf16* __restrict__ W3sw, float* __restrict__ out)
{
    // sA[16][520] (8320 elems) and sH[64][136] (8704 elems) have disjoint
    // live ranges (sA dead after phase-2 MFMA; sH born after the next
    // barrier) — alias them.
    __shared__ bf16 sAH[8704];
    #define SA(p, c) sAH[(p) * 520 + (c)]
    #define SH(r, j) sAH[(r) * 136 + (j)]
    __shared__ int   sNodes[PB][4];
    __shared__ float sSn[ROWS], sCs[ROWS], sDl[ROWS], sDh[ROWS][3];
    __shared__ float sDelta[ROWS][2];

    const int tid  = threadIdx.x;
    const int pBase = blockIdx.x * PB;
    const float tv0 = tvec[0], tv1 = tvec[1], tv2 = tvec[2], tv3 = tvec[3];

    // ---- phase 1: stage sA (all 512) + geometry (tid<64) ----
    {   // sA: 64 (p,i) rows of 256 B; 8 threads per row (32 B each)
        int row = tid >> 3, sg = tid & 7;
        int p = row >> 2, i = row & 3;
        int node = propers[(pBase + p) * 4 + i];
        if (sg == 0) sNodes[p][i] = node;
        const uint4* src = (const uint4*)(encB + (size_t)node * 128 + sg * 16);
        uint4* dst = (uint4*)(&SA(p, i * 128 + sg * 16));
        dst[0] = src[0];
        dst[1] = src[1];
    }
    if (tid < ROWS) {
        int r = tid, p = r >> 2, t = r & 3;
        const int* prow = propers + (pBase + p) * 4;
        int n0 = prow[0], n1 = prow[1], n2 = prow[2], n3 = prow[3];
        const float* c0 = coords + n0 * 12 + t * 3;
        const float* c1 = coords + n1 * 12 + t * 3;
        const float* c2 = coords + n2 * 12 + t * 3;
        const float* c3 = coords + n3 * 12 + t * 3;
        float u1x = c1[0]-c0[0], u1y = c1[1]-c0[1], u1z = c1[2]-c0[2];
        float u2x = c2[0]-c1[0], u2y = c2[1]-c1[1], u2z = c2[2]-c1[2];
        float u3x = c3[0]-c2[0], u3y = c3[1]-c2[1], u3z = c3[2]-c2[2];
        float ax = u1y*u2z - u1z*u2y, ay = u1z*u2x - u1x*u2z, az = u1x*u2y - u1y*u2x;
        float bx = u2y*u3z - u2z*u3y, by = u2z*u3x - u2x*u3z, bz = u2x*u3y - u2y*u3x;
        float u2n = sqrtf(u2x*u2x + u2y*u2y + u2z*u2z);
        float num = u2n * (u1x*bx + u1y*by + u1z*bz);
        float den = ax*bx + ay*by + az*bz;
        float hyp = sqrtf(num*num + den*den);
        float sn, cs;
        if (hyp > 1e-30f) { float ih = 1.0f / hyp; sn = num * ih; cs = den * ih; }
        else { sn = 0.0f; cs = 1.0f; }
        float drx = c0[0]-c3[0], dry = c0[1]-c3[1], drz = c0[2]-c3[2];
        float dl = sqrtf(fmaxf(drx*drx + dry*dry + drz*drz, 1e-12f));
        float il = 1.0f / dl;
        sSn[r] = sn; sCs[r] = cs; sDl[r] = dl;
        sDh[r][0] = drx * il; sDh[r][1] = dry * il; sDh[r][2] = drz * il;
    }
    __syncthreads();

    const int wv = tid >> 6, lane = tid & 63;
    const int fr = lane & 15;      // free-dim index of A/B frags and C/D column
    const int quad = lane >> 4;
    const int m4 = wv & 3;         // M-tile for phases 3/4 (rows m4*16..+15)
    const int nh = wv >> 2;        // N-half for phases 3/4 (cols nh*64..+63)

    // ---- phase 2: g-GEMM, M=16, N=128 (16 cols/wave), K=512 ----
    f32x4 acc = {0.f,0.f,0.f,0.f};
    {
        const bf16* aBase = &SA(fr, quad * 8);
        const bf16* w0b = W0sw + (size_t)wv * 16 * 512 + lane * 8;  // iwv == wv
        #pragma unroll
        for (int kc = 0; kc < 16; ++kc) {
            bf16x8 aF = *(const bf16x8*)(aBase + kc * 32);
            bf16x8 bF = *(const bf16x8*)(w0b + kc * 512);
            acc = __builtin_amdgcn_mfma_f32_16x16x32_bf16(aF, bF, acc, 0, 0, 0);
        }
    }
    __syncthreads();   // sA reads complete before sH (aliased) writes begin

    // ---- h0: rank-4 time/angle/length features + bias, leaky -> sH ----
    {
        int j = wv * 16 + fr;                            // output column
        float w512 = W0[512 * 128 + j], w513 = W0[513 * 128 + j];
        float w514 = W0[514 * 128 + j], w515 = W0[515 * 128 + j];
        float bb = b0[j];
        #pragma unroll
        for (int reg = 0; reg < 4; ++reg) {
            int p = quad * 4 + reg;                      // C/D row = proper index
            float g = acc[reg];
            #pragma unroll
            for (int t = 0; t < 4; ++t) {
                int r = p * 4 + t;
                float tvv = (t == 0) ? tv0 : (t == 1) ? tv1 : (t == 2) ? tv2 : tv3;
                float v = g + tvv * w512 + sSn[r] * w513 + sCs[r] * w514 + sDl[r] * w515 + bb;
                v = v > 0.0f ? v : LEAKY * v;
                SH(r, j) = (bf16)v;
            }
        }
    }
    __syncthreads();

    // ---- phase 3: h1 = leaky(h0 @ W1 + b1); wave quadrant: rows m4*16, cols nh*64 ----
    f32x4 hacc[4];
    #pragma unroll
    for (int nt = 0; nt < 4; ++nt) hacc[nt] = (f32x4){0.f,0.f,0.f,0.f};
    {
        const bf16* aRow = &SH(m4 * 16 + fr, quad * 8);
        const bf16* w1b = W1sw + lane * 8;
        #pragma unroll
        for (int kc = 0; kc < 4; ++kc) {
            bf16x8 aF = *(const bf16x8*)(aRow + kc * 32);
            #pragma unroll
            for (int nt = 0; nt < 4; ++nt) {
                bf16x8 bF = *(const bf16x8*)(w1b + ((nh * 4 + nt) * 4 + kc) * 512);
                hacc[nt] = __builtin_amdgcn_mfma_f32_16x16x32_bf16(aF, bF, hacc[nt], 0, 0, 0);
            }
        }
    }
    __syncthreads();   // all sH reads complete before in-place update
    #pragma unroll
    for (int nt = 0; nt < 4; ++nt) {
        int j = (nh * 4 + nt) * 16 + fr;
        float bb = b1[j];
        #pragma unroll
        for (int reg = 0; reg < 4; ++reg) {
            int r = m4 * 16 + quad * 4 + reg;
            float v = hacc[nt][reg] + bb;
            v = v > 0.0f ? v : LEAKY * v;
            SH(r, j) = (bf16)v;
        }
    }
    __syncthreads();

    // ---- phase 4: h2 = leaky(h1 @ W2 + b2) ----
    #pragma unroll
    for (int nt = 0; nt < 4; ++nt) hacc[nt] = (f32x4){0.f,0.f,0.f,0.f};
    {
        const bf16* aRow = &SH(m4 * 16 + fr, quad * 8);
        const bf16* w2b = W2sw + lane * 8;
        #pragma unroll
        for (int kc = 0; kc < 4; ++kc) {
            bf16x8 aF = *(const bf16x8*)(aRow + kc * 32);
            #pragma unroll
            for (int nt = 0; nt < 4; ++nt) {
                bf16x8 bF = *(const bf16x8*)(w2b + ((nh * 4 + nt) * 4 + kc) * 512);
                hacc[nt] = __builtin_amdgcn_mfma_f32_16x16x32_bf16(aF, bF, hacc[nt], 0, 0, 0);
            }
        }
    }
    __syncthreads();
    #pragma unroll
    for (int nt = 0; nt < 4; ++nt) {
        int j = (nh * 4 + nt) * 16 + fr;
        float bb = b2[j];
        #pragma unroll
        for (int reg = 0; reg < 4; ++reg) {
            int r = m4 * 16 + quad * 4 + reg;
            float v = hacc[nt][reg] + bb;
            v = v > 0.0f ? v : LEAKY * v;
            SH(r, j) = (bf16)v;
        }
    }
    __syncthreads();

    // ---- phase 5: delta = h2 @ W3 + b3 (W3 zero-padded to 16 cols); waves 0-3 ----
    if (wv < 4) {
        f32x4 dacc = {0.f,0.f,0.f,0.f};
        const bf16* aRow = &SH(wv * 16 + fr, quad * 8);
        const bf16* w3b = W3sw + lane * 8;
        #pragma unroll
        for (int kc = 0; kc < 4; ++kc) {
            bf16x8 aF = *(const bf16x8*)(aRow + kc * 32);
            bf16x8 bF = *(const bf16x8*)(w3b + kc * 512);
            dacc = __builtin_amdgcn_mfma_f32_16x16x32_bf16(aF, bF, dacc, 0, 0, 0);
        }
        if (fr < 2) {
            float bb = b3[fr];
            #pragma unroll
            for (int reg = 0; reg < 4; ++reg)
                sDelta[wv * 16 + quad * 4 + reg][fr] = dacc[reg] + bb;
        }
    }
    __syncthreads();

    // ---- phase 6: scatter-add (6 atomics per row, 384 total) ----
    if (tid < ROWS * 6) {
        int r = tid / 6, c = tid % 6;
        int p = r >> 2, t = r & 3;
        int side = c / 3, ax = c % 3;
        int node = sNodes[p][side ? 3 : 0];
        float dval = side ? 0.5f * sDelta[r][1] : -0.5f * sDelta[r][0];
        atomicAdd(out + node * 12 + t * 3 + ax, dval * sDh[r][ax]);
    }
    #undef SA
    #undef SH
}

extern "C" void kernel_launch(void* const* d_in, const int* in_sizes, int n_in,
                              void* d_out, int out_size, void* d_ws, size_t ws_size,
                              hipStream_t stream) {
    const float* coords  = (const float*)d_in[0];
    const int*   propers = (const int*)d_in[1];
    const float* encoded = (const float*)d_in[2];
    const float* tvec    = (const float*)d_in[3];
    const float* answer  = (const float*)d_in[4];
    const float* W0 = (const float*)d_in[5];
    const float* b0 = (const float*)d_in[6];
    const float* W1 = (const float*)d_in[7];
    const float* b1 = (const float*)d_in[8];
    const float* W2 = (const float*)d_in[9];
    const float* b2 = (const float*)d_in[10];
    const float* W3 = (const float*)d_in[11];
    const float* b3 = (const float*)d_in[12];
    float* out = (float*)d_out;
    char* ws = (char*)d_ws;
    bf16* encB = (bf16*)(ws + OFF_ENCB);
    bf16* W0sw = (bf16*)(ws + OFF_W0SW);
    bf16* W1sw = (bf16*)(ws + OFF_W1SW);
    bf16* W2sw = (bf16*)(ws + OFF_W2SW);
    bf16* W3sw = (bf16*)(ws + OFF_W3SW);

    int prep_blocks = (PR_TOTAL + 255) / 256;
    prep_kernel<<<prep_blocks, 256, 0, stream>>>(encoded, W0, W1, W2, W3, answer,
                                                 encB, W0sw, W1sw, W2sw, W3sw, out);
    main_kernel<<<PP / PB, 512, 0, stream>>>(coords, propers, tvec, W0, b0, b1, b2, b3,
                                             encB, W0sw, W1sw, W2sw, W3sw, out);
}